// Round 16
// baseline (189.065 us; speedup 1.0000x reference)
//
#include <hip/hip_runtime.h>
#include <cstdint>

#define NPRI 33600
#define NGT  256
#define NCLS 80
#define KTOP 13
#define INF_F 1.0e8f
#define EPS_F 1e-7f
#define L10 3.3219280948873623f
#define SLC  8
#define SLEN (NPRI / SLC)          // 4200
#define SCN_T 512
#define NW8 (SCN_T / 64)
#define NIT  ((SLEN + SCN_T - 1) / SCN_T)   // 9, uniform padded trip count
#define CAPI 1536                  // per-slice iou values
#define CAPC 512                   // per-slice cost candidates
#define RFIX 5.5f                  // fixed collect radius (strides); Dmax typically ~4.7
#define PREP_BLKS ((NPRI + 255) / 256)
#define NEGINF __int_as_float(0xff800000)

typedef unsigned long long u64;

__device__ __forceinline__ int get_label(const void* p, int j, int is64) {
    if (is64) return (int)((const long long*)p)[j];
    return ((const int*)p)[j];
}

// ---------- wave helpers (reduce + broadcast) ----------
__device__ __forceinline__ float wave_max_bc_f32(float v) {
    #pragma unroll
    for (int off = 32; off > 0; off >>= 1) v = fmaxf(v, __shfl_down(v, off, 64));
    return __int_as_float(__builtin_amdgcn_readfirstlane(__float_as_int(v)));
}
__device__ __forceinline__ u64 wave_min_bc_u64(u64 v) {
    #pragma unroll
    for (int off = 32; off > 0; off >>= 1) { u64 o = __shfl_down(v, off, 64); v = (o < v) ? o : v; }
    unsigned lo = (unsigned)__builtin_amdgcn_readfirstlane((int)(v & 0xffffffffull));
    unsigned hi = (unsigned)__builtin_amdgcn_readfirstlane((int)(v >> 32));
    return (((u64)hi) << 32) | lo;
}
// f32 multiset per-wave top-13: ballot single-lane elimination preserves duplicates
template<int NSL>
__device__ __forceinline__ void wave_merge_max13_f32(float (&l)[NSL], float* dst, int lane) {
    int p = 0;
    for (int r = 0; r < KTOP; ++r) {
        float cur = NEGINF;
        #pragma unroll
        for (int s = 0; s < NSL; ++s) if (s == p) cur = l[NSL - 1 - s];
        float bm = wave_max_bc_f32(cur);
        u64 m = __ballot(cur == bm && bm != NEGINF);
        int first = __ffsll(m) - 1;
        if (lane == first) p++;
        if (lane == 0) dst[r] = bm;
    }
}
// u64 per-wave top-13 min (keys idx-distinct -> single match per round)
template<int NSL>
__device__ __forceinline__ void wave_merge_minN(u64 (&l)[NSL], u64* dst, int lane) {
    int p = 0;
    for (int r = 0; r < KTOP; ++r) {
        u64 cur = ~0ull;
        #pragma unroll
        for (int s = 0; s < NSL; ++s) if (s == p) cur = l[s];
        u64 bm = wave_min_bc_u64(cur);
        if (cur == bm && bm != ~0ull) p++;
        if (lane == 0) dst[r] = bm;
    }
}

// ---------- exact formulas (verbatim round-2: bit-identical selection) ----------
__device__ __forceinline__ float iou_exact(float4 pb, float areap, float gx1, float gy1,
                                           float gx2, float gy2, float areag) {
    float iw = fmaxf(fminf(pb.z, gx2) - fmaxf(pb.x, gx1), 0.0f);
    float ih = fmaxf(fminf(pb.w, gy2) - fmaxf(pb.y, gy1), 0.0f);
    float inter = iw * ih;
    return inter / fmaxf(areap + areag - inter, 1e-6f);
}
__device__ __forceinline__ float cost_exact(float4 p2, float gcx, float gcy,
                                            float l, float iou) {
    float dx = p2.x - gcx, dy = p2.y - gcy;
    float dist = sqrtf(dx * dx + dy * dy) / p2.z;
    float soft = exp2f((dist - 3.0f) * L10);
    float sig = 1.0f / (1.0f + expf(-l));
    float dd = iou - sig;
    float bce = fmaxf(l, 0.0f) - l * iou + log1pf(expf(-fabsf(l)));
    float iouc = -logf(iou + EPS_F) * 3.0f;
    return bce * (dd * dd) + iouc + soft;
}

// ---------- prep: detect int64 + init + valid mask + packed array ----------
__global__ __launch_bounds__(256) void k_prep(
        const float* __restrict__ priors, const float* __restrict__ gt,
        const void* labels, const float* __restrict__ pboxes,
        float4* __restrict__ pbp,
        int* count, int* firstgt, int* flag, int* nmulti) {
    __shared__ float4 gbox[NGT];
    __shared__ int    gpad[NGT];
    __shared__ int    bad;
    const int tid = threadIdx.x;
    const int b = blockIdx.x;
    if (b == 0 && tid == 0) { bad = 0; *nmulti = 0; }
    {
        float4 bx = ((const float4*)gt)[tid];
        gbox[tid] = bx;
        gpad[tid] = ((bx.x + bx.y + bx.z + bx.w) > 0.0f) ? 1 : 0;
    }
    __syncthreads();
    if (b == 0 && tid < 128) {
        long long v = ((const long long*)labels)[tid];   // first 1024B: in-bounds either layout
        if (v < 0 || v >= NCLS) atomicOr(&bad, 1);
    }
    int i = b * 256 + tid;
    if (i < NPRI) {
        count[i] = 0; firstgt[i] = NGT;
        float4 pr = ((const float4*)priors)[i];
        float px = pr.x, py = pr.y;
        int v = 0;
        for (int j = 0; j < NGT; ++j) {
            float4 bx = gbox[j];
            float m = fminf(fminf(px - bx.x, py - bx.y), fminf(bx.z - px, bx.w - py));
            if (m > 0.0f && gpad[j]) { v = 1; break; }
        }
        pbp[2 * i]     = ((const float4*)pboxes)[i];
        pbp[2 * i + 1] = make_float4(px, py, pr.z, v ? 1.0f : 0.0f);
    }
    if (b == 0) {
        __syncthreads();
        if (tid == 0) *flag = bad ? 0 : 1;   // 1 => int64 layout
    }
}

// ---------- single-pass sliced scan; prefetch pipeline; single-wave merges ----------
__global__ __launch_bounds__(SCN_T) void k_scan(
        const float* __restrict__ scores,
        const float4* __restrict__ pbp,
        const float* __restrict__ gt, const void* labels, const int* flag,
        float* __restrict__ part_iou, u64* __restrict__ part_cost) {
    const int tid = threadIdx.x, lane = tid & 63, wid = tid >> 6;
    const int j = blockIdx.x, slice = blockIdx.y;
    const int base = slice * SLEN;
    const int lim = base + SLEN;
    const int is64 = *flag;

    const float4 gb = ((const float4*)gt)[j];
    const float gx1 = gb.x, gy1 = gb.y, gx2 = gb.z, gy2 = gb.w;
    const float areag = (gx2 - gx1) * (gy2 - gy1);
    const float gcx = (gx1 + gx2) * 0.5f, gcy = (gy1 + gy2) * 0.5f;
    const int lab = get_label(labels, j, is64);

    __shared__ int s_ni, s_nc, s_mode;
    __shared__ float s_dmax;
    __shared__ float liou[CAPI];
    __shared__ int lcost[CAPC];
    __shared__ float wiof[NW8 * KTOP];   // fI fallback only
    __shared__ u64 wco[NW8 * KTOP];      // mode-2 fallback only
    __shared__ u64 csel[KTOP];
    if (tid == 0) { s_ni = 0; s_nc = 0; }
    __syncthreads();

    // ---- single pass, uniform 9-iter trip, prefetch-pipelined, wave-agg appends ----
    {
        int i = base + tid;                      // always < lim (SLEN > SCN_T)
        float4 pb = pbp[2 * i];
        float4 p2 = pbp[2 * i + 1];
        for (int it = 0; it < NIT; ++it) {
            int inext = i + SCN_T;
            bool nin = (it + 1 < NIT) && (inext < lim);
            float4 nb = make_float4(0.f, 0.f, 0.f, 0.f);
            float4 n2 = make_float4(0.f, 0.f, 0.f, 0.f);
            if (nin) { nb = pbp[2 * inext]; n2 = pbp[2 * inext + 1]; }   // in flight during ballots

            bool inb = (i < lim);
            float iou = 0.0f;
            bool pc = false;
            if (inb) {
                float areap = (pb.z - pb.x) * (pb.w - pb.y);
                float iw = fmaxf(fminf(pb.z, gx2) - fmaxf(pb.x, gx1), 0.0f);
                float ih = fmaxf(fminf(pb.w, gy2) - fmaxf(pb.y, gy1), 0.0f);
                float inter = iw * ih;
                iou = inter / fmaxf(areap + areag - inter, 1e-6f);   // exact
                if (p2.w != 0.0f) {
                    float dx = p2.x - gcx, dy = p2.y - gcy;
                    float rad = p2.z * RFIX;
                    pc = (dx * dx + dy * dy <= rad * rad * (1.0f + 1e-5f));
                }
            }
            bool pi = inb && (iou > 0.0f);
            u64 mi = __ballot(pi);
            if (mi) {
                int lead = __ffsll(mi) - 1;
                int cnt = __popcll(mi);
                int bs = 0;
                if (lane == lead) bs = atomicAdd(&s_ni, cnt);
                bs = __shfl(bs, lead, 64);
                if (pi) {
                    int p = bs + __popcll(mi & ((1ull << lane) - 1ull));
                    if (p < CAPI) liou[p] = iou;
                }
            }
            u64 mc = __ballot(pc);
            if (mc) {
                int lead = __ffsll(mc) - 1;
                int cnt = __popcll(mc);
                int bs = 0;
                if (lane == lead) bs = atomicAdd(&s_nc, cnt);
                bs = __shfl(bs, lead, 64);
                if (pc) {
                    int p = bs + __popcll(mc & ((1ull << lane) - 1ull));
                    if (p < CAPC) lcost[p] = i;
                }
            }
            i = inext; pb = nb; p2 = n2;
        }
    }
    __syncthreads();
    const int ni = s_ni, nc = s_nc;
    const int ncc = (nc < CAPC) ? nc : CAPC;
    const bool fI = (ni > CAPI);

    // ---- parallel single-wave merges: wave 0 = cost, wave 1 = iou ----
    if (wid == 0) {
        u64 lf[KTOP];
        #pragma unroll
        for (int s = 0; s < KTOP; ++s) lf[s] = ~0ull;
        for (int k = lane; k < ncc; k += 64) {   // <=8 per lane; 13-deep list complete
            int i = lcost[k];
            float4 pb = pbp[2 * i];
            float4 p2 = pbp[2 * i + 1];
            float areap = (pb.z - pb.x) * (pb.w - pb.y);
            float iou = iou_exact(pb, areap, gx1, gy1, gx2, gy2, areag);
            float ec = cost_exact(p2, gcx, gcy, scores[(size_t)i * NCLS + lab], iou);
            u64 ck = (((u64)__float_as_uint(ec)) << 32) | (unsigned)i;
            if (ck < lf[KTOP - 1]) {
                lf[KTOP - 1] = ck;
                #pragma unroll
                for (int s = KTOP - 1; s > 0; --s)
                    if (lf[s] < lf[s - 1]) { u64 t = lf[s]; lf[s] = lf[s - 1]; lf[s - 1] = t; }
            }
        }
        wave_merge_minN<KTOP>(lf, csel, lane);
        if (lane == 0) {
            u64 tk = csel[KTOP - 1];
            int mode; float dmax = 0.0f;
            if (tk == ~0ull) mode = 2;               // <13 candidates in RFIX ball
            else {
                float tau = __uint_as_float((unsigned)(tk >> 32));
                if (!(tau < 9.0e7f)) mode = 2;       // INF-ambiguity zone
                else {
                    dmax = 3.0f + __log2f(tau + 1e-5f) * (1.0f / L10) + 4e-3f;
                    mode = (dmax > RFIX || nc > CAPC) ? 1 : 0;
                }
            }
            s_mode = mode; s_dmax = dmax;
        }
    } else if (wid == 1 && !fI) {
        float lf[KTOP];
        #pragma unroll
        for (int s = 0; s < KTOP; ++s) lf[s] = NEGINF;
        int nn = (ni < CAPI) ? ni : CAPI;
        for (int k = lane; k < nn; k += 64) {    // 13-deep retains any lane's top-13
            float v = liou[k];
            if (v > lf[0]) {
                lf[0] = v;
                #pragma unroll
                for (int s = 0; s < KTOP - 1; ++s)
                    if (lf[s] > lf[s + 1]) { float t = lf[s]; lf[s] = lf[s + 1]; lf[s + 1] = t; }
            }
        }
        wave_merge_max13_f32<KTOP>(lf, part_iou + ((size_t)j * SLC + slice) * KTOP, lane);
    }
    __syncthreads();

    if (fI) {   // rare: iou list overflowed -> exact full-slice scan (two-stage merge)
        float lf[KTOP];
        #pragma unroll
        for (int s = 0; s < KTOP; ++s) lf[s] = NEGINF;
        for (int i = base + tid; i < lim; i += SCN_T) {
            float4 pb = pbp[2 * i];
            float areap = (pb.z - pb.x) * (pb.w - pb.y);
            float iou = iou_exact(pb, areap, gx1, gy1, gx2, gy2, areag);
            if (iou > lf[0]) {
                lf[0] = iou;
                #pragma unroll
                for (int s = 0; s < KTOP - 1; ++s)
                    if (lf[s] > lf[s + 1]) { float t = lf[s]; lf[s] = lf[s + 1]; lf[s + 1] = t; }
            }
        }
        wave_merge_max13_f32<KTOP>(lf, &wiof[wid * KTOP], lane);
        __syncthreads();
        if (wid == 0) {
            float* dpi = part_iou + ((size_t)j * SLC + slice) * KTOP;
            int p = 0;
            for (int r = 0; r < KTOP; ++r) {
                float cur = (lane < NW8 && p < KTOP) ? wiof[lane * KTOP + p] : NEGINF;
                float bm = wave_max_bc_f32(cur);
                u64 m = __ballot(cur == bm && bm != NEGINF);
                int first = __ffsll(m) - 1;
                if (lane == first) p++;
                if (lane == 0) dpi[r] = bm;
            }
        }
        __syncthreads();
    }

    int mode = s_mode;
    if (mode == 1) {   // re-collect at the sound radius Dmax' (rare)
        const float dmax = s_dmax;
        if (tid == 0) s_nc = 0;
        __syncthreads();
        for (int i = base + tid; i < lim; i += SCN_T) {
            float4 p2 = pbp[2 * i + 1];
            if (p2.w != 0.0f) {
                float dx = p2.x - gcx, dy = p2.y - gcy;
                float rad = p2.z * dmax;
                if (dx * dx + dy * dy <= rad * rad * (1.0f + 1e-5f)) {
                    int p = atomicAdd(&s_nc, 1);
                    if (p < CAPC) lcost[p] = i;
                }
            }
        }
        __syncthreads();
        int nc2 = s_nc;
        if (nc2 <= CAPC) {
            if (wid == 0) {
                u64 lf[KTOP];
                #pragma unroll
                for (int s = 0; s < KTOP; ++s) lf[s] = ~0ull;
                for (int k = lane; k < nc2; k += 64) {
                    int i = lcost[k];
                    float4 pb = pbp[2 * i];
                    float4 p2 = pbp[2 * i + 1];
                    float areap = (pb.z - pb.x) * (pb.w - pb.y);
                    float iou = iou_exact(pb, areap, gx1, gy1, gx2, gy2, areag);
                    float ec = cost_exact(p2, gcx, gcy, scores[(size_t)i * NCLS + lab], iou);
                    u64 ck = (((u64)__float_as_uint(ec)) << 32) | (unsigned)i;
                    if (ck < lf[KTOP - 1]) {
                        lf[KTOP - 1] = ck;
                        #pragma unroll
                        for (int s = KTOP - 1; s > 0; --s)
                            if (lf[s] < lf[s - 1]) { u64 t = lf[s]; lf[s] = lf[s - 1]; lf[s - 1] = t; }
                    }
                }
                wave_merge_minN<KTOP>(lf, csel, lane);
            }
        } else {
            mode = 2;   // uniform (s_nc shared)
        }
        __syncthreads();
    }
    if (mode == 2) {   // exact full slice scan (round-2 semantics; correctness net)
        u64 lf[KTOP];
        #pragma unroll
        for (int s = 0; s < KTOP; ++s) lf[s] = ~0ull;
        for (int i = base + tid; i < lim; i += SCN_T) {
            float4 pb = pbp[2 * i];
            float4 p2 = pbp[2 * i + 1];
            float areap = (pb.z - pb.x) * (pb.w - pb.y);
            float iou = iou_exact(pb, areap, gx1, gy1, gx2, gy2, areag);
            float ec = INF_F;
            if (p2.w != 0.0f) ec = cost_exact(p2, gcx, gcy, scores[(size_t)i * NCLS + lab], iou);
            u64 k2 = (((u64)__float_as_uint(ec)) << 32) | (unsigned)i;
            if (k2 < lf[KTOP - 1]) {
                lf[KTOP - 1] = k2;
                #pragma unroll
                for (int s = KTOP - 1; s > 0; --s)
                    if (lf[s] < lf[s - 1]) { u64 t = lf[s]; lf[s] = lf[s - 1]; lf[s - 1] = t; }
            }
        }
        wave_merge_minN<KTOP>(lf, &wco[wid * KTOP], lane);
        __syncthreads();
        if (wid == 0) {
            int p = 0;
            for (int r = 0; r < KTOP; ++r) {
                u64 cur = (lane < NW8 && p < KTOP) ? wco[lane * KTOP + p] : ~0ull;
                u64 bm = wave_min_bc_u64(cur);
                if (cur == bm && bm != ~0ull) p++;
                if (lane == 0) csel[r] = bm;
            }
        }
        __syncthreads();
    }
    if (tid < KTOP) {
        u64* dpc = part_cost + ((size_t)j * SLC + slice) * KTOP;
        dpc[tid] = csel[tid];
    }
}

// ---------- merge 8 slices per GT (104 entries, 2/lane), compute ks, scatter ----------
__global__ __launch_bounds__(64) void k_merge(
        const float* __restrict__ part_iou, const u64* __restrict__ part_cost,
        int* count, int* firstgt) {
    const int j = blockIdx.x;
    const int lane = threadIdx.x;
    __shared__ float tiou[KTOP];
    __shared__ u64 cfin[KTOP];

    float a = (lane < SLC * KTOP) ? part_iou[(size_t)j * SLC * KTOP + lane] : NEGINF;
    float b = (lane + 64 < SLC * KTOP) ? part_iou[(size_t)j * SLC * KTOP + lane + 64] : NEGINF;
    float l2[2] = { fminf(a, b), fmaxf(a, b) };          // ascending
    wave_merge_max13_f32<2>(l2, tiou, lane);

    u64 ka = (lane < SLC * KTOP) ? part_cost[(size_t)j * SLC * KTOP + lane] : ~0ull;
    u64 kb = (lane + 64 < SLC * KTOP) ? part_cost[(size_t)j * SLC * KTOP + lane + 64] : ~0ull;
    u64 c2[2] = { (ka < kb) ? ka : kb, (ka < kb) ? kb : ka };   // ascending
    wave_merge_minN<2>(c2, cfin, lane);
    __syncthreads();

    float tsum = 0.0f;
    #pragma unroll
    for (int r = 0; r < KTOP; ++r) {
        float v = tiou[r];                                // descending order (matches ref sum)
        tsum += (v == NEGINF) ? 0.0f : v;
    }
    int ks = (int)tsum;
    if (ks < 1) ks = 1;
    if (lane < KTOP && lane < ks) {
        u64 mine = cfin[lane];
        if (mine != ~0ull) {
            int idx = (int)(unsigned)(mine & 0xFFFFFFFFull);
            atomicAdd(&count[idx], 1);
            atomicMin(&firstgt[idx], j);
        }
    }
}

// ---------- per-prior finalize; multi-matched priors -> worklist ----------
__global__ __launch_bounds__(256) void k_assign(
        const float4* __restrict__ pbp, const float* __restrict__ gt,
        const void* labels, const int* flag,
        const int* __restrict__ count, const int* __restrict__ firstgt,
        int* nmulti, int* mlist, float* __restrict__ out) {
    __shared__ float4 gbox[NGT];
    __shared__ int glab[NGT];
    __shared__ float gareas[NGT];
    int tid = threadIdx.x;
    int is64 = *flag;
    {
        float4 b = ((const float4*)gt)[tid];
        gbox[tid] = b;
        glab[tid] = get_label(labels, tid, is64);
        gareas[tid] = (b.z - b.x) * (b.w - b.y);
    }
    __syncthreads();
    int i = blockIdx.x * 256 + tid;
    if (i >= NPRI) return;
    float4 p2 = pbp[2 * i + 1];
    int v = (p2.w != 0.0f) ? 1 : 0;
    int c = count[i];
    float o0 = 0.0f, o1 = -INF_F, o2 = -1.0f;
    if (v && c == 1) {
        int j = firstgt[i];
        float4 pb = pbp[2 * i];
        float areap = (pb.z - pb.x) * (pb.w - pb.y);
        float4 g = gbox[j];
        float iw = fmaxf(fminf(pb.z, g.z) - fmaxf(pb.x, g.x), 0.0f);
        float ih = fmaxf(fminf(pb.w, g.w) - fmaxf(pb.y, g.y), 0.0f);
        float inter = iw * ih;
        float iou = inter / fmaxf(areap + gareas[j] - inter, 1e-6f);
        o0 = (float)(j + 1); o1 = iou; o2 = (float)glab[j];
    } else if (v && c > 1) {
        int pos = atomicAdd(nmulti, 1);
        mlist[pos] = i;
    }
    out[i] = o0;
    out[NPRI + i] = o1;
    out[2 * NPRI + i] = o2;
}

// ---------- one block per multi prior: block argmin over 256 GT costs ----------
__global__ __launch_bounds__(256) void k_multi(
        const float* __restrict__ scores,
        const float4* __restrict__ pbp, const float* __restrict__ gt,
        const void* labels, const int* flag,
        const int* __restrict__ nmulti, const int* __restrict__ mlist,
        float* __restrict__ out) {
    __shared__ float4 gbox[NGT];
    __shared__ int glab[NGT];
    __shared__ float gcxs[NGT], gcys[NGT], gareas[NGT];
    __shared__ u64 red4[4];
    const int tid = threadIdx.x;
    const int is64 = *flag;
    {
        float4 b = ((const float4*)gt)[tid];
        gbox[tid] = b;
        glab[tid] = get_label(labels, tid, is64);
        gcxs[tid] = (b.x + b.z) * 0.5f;
        gcys[tid] = (b.y + b.w) * 0.5f;
        gareas[tid] = (b.z - b.x) * (b.w - b.y);
    }
    __syncthreads();
    const int nm = *nmulti;
    const int j = tid;
    for (int m = blockIdx.x; m < nm; m += gridDim.x) {
        const int i = mlist[m];
        float4 pb = pbp[2 * i];
        float4 p2 = pbp[2 * i + 1];
        float areap = (pb.z - pb.x) * (pb.w - pb.y);

        float4 g = gbox[j];
        float iw = fmaxf(fminf(pb.z, g.z) - fmaxf(pb.x, g.x), 0.0f);
        float ih = fmaxf(fminf(pb.w, g.w) - fmaxf(pb.y, g.y), 0.0f);
        float inter = iw * ih;
        float iou = inter / fmaxf(areap + gareas[j] - inter, 1e-6f);
        float dx = p2.x - gcxs[j], dy = p2.y - gcys[j];
        float dist = sqrtf(dx * dx + dy * dy) / p2.z;
        float soft = exp2f((dist - 3.0f) * L10);
        float l = scores[(size_t)i * NCLS + glab[j]];
        float sig = 1.0f / (1.0f + expf(-l));
        float dd = iou - sig;
        float bce = fmaxf(l, 0.0f) - l * iou + log1pf(expf(-fabsf(l)));
        float cost = bce * (dd * dd) + (-logf(iou + EPS_F) * 3.0f) + soft;

        u64 key = (((u64)__float_as_uint(cost)) << 32) | (unsigned)j;
        u64 v = key;
        #pragma unroll
        for (int off = 32; off > 0; off >>= 1) {
            u64 o = __shfl_down(v, off, 64);
            v = (o < v) ? o : v;
        }
        if ((tid & 63) == 0) red4[tid >> 6] = v;
        __syncthreads();
        u64 best = red4[0];
        #pragma unroll
        for (int q = 1; q < 4; ++q) best = (red4[q] < best) ? red4[q] : best;
        if (key == best) {
            out[i] = (float)(j + 1);
            out[NPRI + i] = iou;
            out[2 * NPRI + i] = (float)glab[j];
        }
        __syncthreads();
    }
}

extern "C" void kernel_launch(void* const* d_in, const int* in_sizes, int n_in,
                              void* d_out, int out_size, void* d_ws, size_t ws_size,
                              hipStream_t stream) {
    const float* scores = (const float*)d_in[0];
    const float* priors = (const float*)d_in[1];
    const float* pboxes = (const float*)d_in[2];
    const float* gt     = (const float*)d_in[3];
    const void*  labels = d_in[4];
    float* out = (float*)d_out;

    char* ws = (char*)d_ws;
    size_t off = 0;
    auto alloc = [&](size_t bytes) { size_t o = off; off = (off + bytes + 255) & ~(size_t)255; return o; };
    int*    flag     = (int*)(ws + alloc(4));
    int*    nmulti   = (int*)(ws + alloc(4));
    int*    count    = (int*)(ws + alloc((size_t)NPRI * 4));
    int*    firstgt  = (int*)(ws + alloc((size_t)NPRI * 4));
    int*    mlist    = (int*)(ws + alloc((size_t)NPRI * 4));
    float*  part_iou = (float*)(ws + alloc((size_t)NGT * SLC * KTOP * 4));
    u64*    part_cost= (u64*)(ws + alloc((size_t)NGT * SLC * KTOP * 8));
    float4* pbp      = (float4*)(ws + alloc((size_t)NPRI * 32));
    (void)ws_size;

    hipLaunchKernelGGL(k_prep, dim3(PREP_BLKS), dim3(256), 0, stream,
                       priors, gt, labels, pboxes, pbp, count, firstgt, flag, nmulti);
    hipLaunchKernelGGL(k_scan, dim3(NGT, SLC), dim3(SCN_T), 0, stream,
                       scores, pbp, gt, labels, flag, part_iou, part_cost);
    hipLaunchKernelGGL(k_merge, dim3(NGT), dim3(64), 0, stream,
                       part_iou, part_cost, count, firstgt);
    hipLaunchKernelGGL(k_assign, dim3((NPRI + 255) / 256), dim3(256), 0, stream,
                       pbp, gt, labels, flag, count, firstgt, nmulti, mlist, out);
    hipLaunchKernelGGL(k_multi, dim3(256), dim3(256), 0, stream,
                       scores, pbp, gt, labels, flag, nmulti, mlist, out);
}

// Round 17
// 150.649 us; speedup vs baseline: 1.2550x; 1.2550x over previous
//
#include <hip/hip_runtime.h>
#include <cstdint>

#define NPRI 33600
#define NGT  256
#define NCLS 80
#define KTOP 13
#define INF_F 1.0e8f
#define EPS_F 1e-7f
#define L10 3.3219280948873623f
#define SLC  4
#define SLEN (NPRI / SLC)          // 8400
#define SCN_T 512
#define NW8 (SCN_T / 64)
#define NIT  ((SLEN + SCN_T - 1) / SCN_T)   // 17, uniform padded trip count
#define CAPI 1536                  // per-slice iou values
#define CAPC 512                   // per-slice cost candidates
#define RFIX 5.5f                  // fixed collect radius (strides); Dmax typically ~4.7
#define PREP_BLKS ((NPRI + 255) / 256)
#define NEGINF __int_as_float(0xff800000)

typedef unsigned long long u64;

__device__ __forceinline__ int get_label(const void* p, int j, int is64) {
    if (is64) return (int)((const long long*)p)[j];
    return ((const int*)p)[j];
}

// ---------- wave helpers (reduce + broadcast) ----------
__device__ __forceinline__ float wave_max_bc_f32(float v) {
    #pragma unroll
    for (int off = 32; off > 0; off >>= 1) v = fmaxf(v, __shfl_down(v, off, 64));
    return __int_as_float(__builtin_amdgcn_readfirstlane(__float_as_int(v)));
}
__device__ __forceinline__ u64 wave_min_bc_u64(u64 v) {
    #pragma unroll
    for (int off = 32; off > 0; off >>= 1) { u64 o = __shfl_down(v, off, 64); v = (o < v) ? o : v; }
    unsigned lo = (unsigned)__builtin_amdgcn_readfirstlane((int)(v & 0xffffffffull));
    unsigned hi = (unsigned)__builtin_amdgcn_readfirstlane((int)(v >> 32));
    return (((u64)hi) << 32) | lo;
}
// f32 multiset per-wave top-13: ballot single-lane elimination preserves duplicates
template<int NSL>
__device__ __forceinline__ void wave_merge_max13_f32(float (&l)[NSL], float* dst, int lane) {
    int p = 0;
    for (int r = 0; r < KTOP; ++r) {
        float cur = NEGINF;
        #pragma unroll
        for (int s = 0; s < NSL; ++s) if (s == p) cur = l[NSL - 1 - s];
        float bm = wave_max_bc_f32(cur);
        u64 m = __ballot(cur == bm && bm != NEGINF);
        int first = __ffsll(m) - 1;
        if (lane == first) p++;
        if (lane == 0) dst[r] = bm;
    }
}
// u64 per-wave top-13 min (keys idx-distinct -> single match per round)
template<int NSL>
__device__ __forceinline__ void wave_merge_minN(u64 (&l)[NSL], u64* dst, int lane) {
    int p = 0;
    for (int r = 0; r < KTOP; ++r) {
        u64 cur = ~0ull;
        #pragma unroll
        for (int s = 0; s < NSL; ++s) if (s == p) cur = l[s];
        u64 bm = wave_min_bc_u64(cur);
        if (cur == bm && bm != ~0ull) p++;
        if (lane == 0) dst[r] = bm;
    }
}

// ---------- exact formulas (verbatim round-2: bit-identical selection) ----------
__device__ __forceinline__ float iou_exact(float4 pb, float areap, float gx1, float gy1,
                                           float gx2, float gy2, float areag) {
    float iw = fmaxf(fminf(pb.z, gx2) - fmaxf(pb.x, gx1), 0.0f);
    float ih = fmaxf(fminf(pb.w, gy2) - fmaxf(pb.y, gy1), 0.0f);
    float inter = iw * ih;
    return inter / fmaxf(areap + areag - inter, 1e-6f);
}
__device__ __forceinline__ float cost_exact(float4 p2, float gcx, float gcy,
                                            float l, float iou) {
    float dx = p2.x - gcx, dy = p2.y - gcy;
    float dist = sqrtf(dx * dx + dy * dy) / p2.z;
    float soft = exp2f((dist - 3.0f) * L10);
    float sig = 1.0f / (1.0f + expf(-l));
    float dd = iou - sig;
    float bce = fmaxf(l, 0.0f) - l * iou + log1pf(expf(-fabsf(l)));
    float iouc = -logf(iou + EPS_F) * 3.0f;
    return bce * (dd * dd) + iouc + soft;
}

// ---------- prep: detect int64 + init + valid mask + packed array ----------
__global__ __launch_bounds__(256) void k_prep(
        const float* __restrict__ priors, const float* __restrict__ gt,
        const void* labels, const float* __restrict__ pboxes,
        float4* __restrict__ pbp,
        int* count, int* firstgt, int* flag, int* nmulti) {
    __shared__ float4 gbox[NGT];
    __shared__ int    gpad[NGT];
    __shared__ int    bad;
    const int tid = threadIdx.x;
    const int b = blockIdx.x;
    if (b == 0 && tid == 0) { bad = 0; *nmulti = 0; }
    {
        float4 bx = ((const float4*)gt)[tid];
        gbox[tid] = bx;
        gpad[tid] = ((bx.x + bx.y + bx.z + bx.w) > 0.0f) ? 1 : 0;
    }
    __syncthreads();
    if (b == 0 && tid < 128) {
        long long v = ((const long long*)labels)[tid];   // first 1024B: in-bounds either layout
        if (v < 0 || v >= NCLS) atomicOr(&bad, 1);
    }
    int i = b * 256 + tid;
    if (i < NPRI) {
        count[i] = 0; firstgt[i] = NGT;
        float4 pr = ((const float4*)priors)[i];
        float px = pr.x, py = pr.y;
        int v = 0;
        for (int j = 0; j < NGT; ++j) {
            float4 bx = gbox[j];
            float m = fminf(fminf(px - bx.x, py - bx.y), fminf(bx.z - px, bx.w - py));
            if (m > 0.0f && gpad[j]) { v = 1; break; }
        }
        pbp[2 * i]     = ((const float4*)pboxes)[i];
        pbp[2 * i + 1] = make_float4(px, py, pr.z, v ? 1.0f : 0.0f);
    }
    if (b == 0) {
        __syncthreads();
        if (tid == 0) *flag = bad ? 0 : 1;   // 1 => int64 layout
    }
}

// ---------- single-pass sliced scan; prefetch pipeline; single-wave merges ----------
__global__ __launch_bounds__(SCN_T) void k_scan(
        const float* __restrict__ scores,
        const float4* __restrict__ pbp,
        const float* __restrict__ gt, const void* labels, const int* flag,
        float* __restrict__ part_iou, u64* __restrict__ part_cost) {
    const int tid = threadIdx.x, lane = tid & 63, wid = tid >> 6;
    const int j = blockIdx.x, slice = blockIdx.y;
    const int base = slice * SLEN;
    const int lim = base + SLEN;
    const int is64 = *flag;

    const float4 gb = ((const float4*)gt)[j];
    const float gx1 = gb.x, gy1 = gb.y, gx2 = gb.z, gy2 = gb.w;
    const float areag = (gx2 - gx1) * (gy2 - gy1);
    const float gcx = (gx1 + gx2) * 0.5f, gcy = (gy1 + gy2) * 0.5f;
    const int lab = get_label(labels, j, is64);

    __shared__ int s_ni, s_nc, s_mode;
    __shared__ float s_dmax;
    __shared__ float liou[CAPI];
    __shared__ int lcost[CAPC];
    __shared__ float wiof[NW8 * KTOP];   // fI fallback only
    __shared__ u64 wco[NW8 * KTOP];      // mode-2 fallback only
    __shared__ u64 csel[KTOP];
    if (tid == 0) { s_ni = 0; s_nc = 0; }
    __syncthreads();

    // ---- single pass, uniform 17-iter trip, prefetch-pipelined, wave-agg appends ----
    {
        int i = base + tid;                      // always < lim (SLEN > SCN_T)
        float4 pb = pbp[2 * i];
        float4 p2 = pbp[2 * i + 1];
        for (int it = 0; it < NIT; ++it) {
            int inext = i + SCN_T;
            bool nin = (it + 1 < NIT) && (inext < lim);
            float4 nb = make_float4(0.f, 0.f, 0.f, 0.f);
            float4 n2 = make_float4(0.f, 0.f, 0.f, 0.f);
            if (nin) { nb = pbp[2 * inext]; n2 = pbp[2 * inext + 1]; }   // in flight during ballots

            bool inb = (i < lim);
            float iou = 0.0f;
            bool pc = false;
            if (inb) {
                float areap = (pb.z - pb.x) * (pb.w - pb.y);
                float iw = fmaxf(fminf(pb.z, gx2) - fmaxf(pb.x, gx1), 0.0f);
                float ih = fmaxf(fminf(pb.w, gy2) - fmaxf(pb.y, gy1), 0.0f);
                float inter = iw * ih;
                iou = inter / fmaxf(areap + areag - inter, 1e-6f);   // exact
                if (p2.w != 0.0f) {
                    float dx = p2.x - gcx, dy = p2.y - gcy;
                    float rad = p2.z * RFIX;
                    pc = (dx * dx + dy * dy <= rad * rad * (1.0f + 1e-5f));
                }
            }
            bool pi = inb && (iou > 0.0f);
            u64 mi = __ballot(pi);
            if (mi) {
                int lead = __ffsll(mi) - 1;
                int cnt = __popcll(mi);
                int bs = 0;
                if (lane == lead) bs = atomicAdd(&s_ni, cnt);
                bs = __shfl(bs, lead, 64);
                if (pi) {
                    int p = bs + __popcll(mi & ((1ull << lane) - 1ull));
                    if (p < CAPI) liou[p] = iou;
                }
            }
            u64 mc = __ballot(pc);
            if (mc) {
                int lead = __ffsll(mc) - 1;
                int cnt = __popcll(mc);
                int bs = 0;
                if (lane == lead) bs = atomicAdd(&s_nc, cnt);
                bs = __shfl(bs, lead, 64);
                if (pc) {
                    int p = bs + __popcll(mc & ((1ull << lane) - 1ull));
                    if (p < CAPC) lcost[p] = i;
                }
            }
            i = inext; pb = nb; p2 = n2;
        }
    }
    __syncthreads();
    const int ni = s_ni, nc = s_nc;
    const int ncc = (nc < CAPC) ? nc : CAPC;
    const bool fI = (ni > CAPI);

    // ---- parallel single-wave merges: wave 0 = cost, wave 1 = iou ----
    if (wid == 0) {
        u64 lf[KTOP];
        #pragma unroll
        for (int s = 0; s < KTOP; ++s) lf[s] = ~0ull;
        for (int k = lane; k < ncc; k += 64) {   // <=8 per lane; 13-deep list complete
            int i = lcost[k];
            float4 pb = pbp[2 * i];
            float4 p2 = pbp[2 * i + 1];
            float areap = (pb.z - pb.x) * (pb.w - pb.y);
            float iou = iou_exact(pb, areap, gx1, gy1, gx2, gy2, areag);
            float ec = cost_exact(p2, gcx, gcy, scores[(size_t)i * NCLS + lab], iou);
            u64 ck = (((u64)__float_as_uint(ec)) << 32) | (unsigned)i;
            if (ck < lf[KTOP - 1]) {
                lf[KTOP - 1] = ck;
                #pragma unroll
                for (int s = KTOP - 1; s > 0; --s)
                    if (lf[s] < lf[s - 1]) { u64 t = lf[s]; lf[s] = lf[s - 1]; lf[s - 1] = t; }
            }
        }
        wave_merge_minN<KTOP>(lf, csel, lane);
        if (lane == 0) {
            u64 tk = csel[KTOP - 1];
            int mode; float dmax = 0.0f;
            if (tk == ~0ull) mode = 2;               // <13 candidates in RFIX ball
            else {
                float tau = __uint_as_float((unsigned)(tk >> 32));
                if (!(tau < 9.0e7f)) mode = 2;       // INF-ambiguity zone
                else {
                    dmax = 3.0f + __log2f(tau + 1e-5f) * (1.0f / L10) + 4e-3f;
                    mode = (dmax > RFIX || nc > CAPC) ? 1 : 0;
                }
            }
            s_mode = mode; s_dmax = dmax;
        }
    } else if (wid == 1 && !fI) {
        float lf[KTOP];
        #pragma unroll
        for (int s = 0; s < KTOP; ++s) lf[s] = NEGINF;
        int nn = (ni < CAPI) ? ni : CAPI;
        for (int k = lane; k < nn; k += 64) {    // <=24 per lane; 13-deep retains any lane's top-13
            float v = liou[k];
            if (v > lf[0]) {
                lf[0] = v;
                #pragma unroll
                for (int s = 0; s < KTOP - 1; ++s)
                    if (lf[s] > lf[s + 1]) { float t = lf[s]; lf[s] = lf[s + 1]; lf[s + 1] = t; }
            }
        }
        wave_merge_max13_f32<KTOP>(lf, part_iou + ((size_t)j * SLC + slice) * KTOP, lane);
    }
    __syncthreads();

    if (fI) {   // rare: iou list overflowed -> exact full-slice scan (two-stage merge)
        float lf[KTOP];
        #pragma unroll
        for (int s = 0; s < KTOP; ++s) lf[s] = NEGINF;
        for (int i = base + tid; i < lim; i += SCN_T) {
            float4 pb = pbp[2 * i];
            float areap = (pb.z - pb.x) * (pb.w - pb.y);
            float iou = iou_exact(pb, areap, gx1, gy1, gx2, gy2, areag);
            if (iou > lf[0]) {
                lf[0] = iou;
                #pragma unroll
                for (int s = 0; s < KTOP - 1; ++s)
                    if (lf[s] > lf[s + 1]) { float t = lf[s]; lf[s] = lf[s + 1]; lf[s + 1] = t; }
            }
        }
        wave_merge_max13_f32<KTOP>(lf, &wiof[wid * KTOP], lane);
        __syncthreads();
        if (wid == 0) {
            float* dpi = part_iou + ((size_t)j * SLC + slice) * KTOP;
            int p = 0;
            for (int r = 0; r < KTOP; ++r) {
                float cur = (lane < NW8 && p < KTOP) ? wiof[lane * KTOP + p] : NEGINF;
                float bm = wave_max_bc_f32(cur);
                u64 m = __ballot(cur == bm && bm != NEGINF);
                int first = __ffsll(m) - 1;
                if (lane == first) p++;
                if (lane == 0) dpi[r] = bm;
            }
        }
        __syncthreads();
    }

    int mode = s_mode;
    if (mode == 1) {   // re-collect at the sound radius Dmax' (rare)
        const float dmax = s_dmax;
        if (tid == 0) s_nc = 0;
        __syncthreads();
        for (int i = base + tid; i < lim; i += SCN_T) {
            float4 p2 = pbp[2 * i + 1];
            if (p2.w != 0.0f) {
                float dx = p2.x - gcx, dy = p2.y - gcy;
                float rad = p2.z * dmax;
                if (dx * dx + dy * dy <= rad * rad * (1.0f + 1e-5f)) {
                    int p = atomicAdd(&s_nc, 1);
                    if (p < CAPC) lcost[p] = i;
                }
            }
        }
        __syncthreads();
        int nc2 = s_nc;
        if (nc2 <= CAPC) {
            if (wid == 0) {
                u64 lf[KTOP];
                #pragma unroll
                for (int s = 0; s < KTOP; ++s) lf[s] = ~0ull;
                for (int k = lane; k < nc2; k += 64) {
                    int i = lcost[k];
                    float4 pb = pbp[2 * i];
                    float4 p2 = pbp[2 * i + 1];
                    float areap = (pb.z - pb.x) * (pb.w - pb.y);
                    float iou = iou_exact(pb, areap, gx1, gy1, gx2, gy2, areag);
                    float ec = cost_exact(p2, gcx, gcy, scores[(size_t)i * NCLS + lab], iou);
                    u64 ck = (((u64)__float_as_uint(ec)) << 32) | (unsigned)i;
                    if (ck < lf[KTOP - 1]) {
                        lf[KTOP - 1] = ck;
                        #pragma unroll
                        for (int s = KTOP - 1; s > 0; --s)
                            if (lf[s] < lf[s - 1]) { u64 t = lf[s]; lf[s] = lf[s - 1]; lf[s - 1] = t; }
                    }
                }
                wave_merge_minN<KTOP>(lf, csel, lane);
            }
        } else {
            mode = 2;   // uniform (s_nc shared)
        }
        __syncthreads();
    }
    if (mode == 2) {   // exact full slice scan (round-2 semantics; correctness net)
        u64 lf[KTOP];
        #pragma unroll
        for (int s = 0; s < KTOP; ++s) lf[s] = ~0ull;
        for (int i = base + tid; i < lim; i += SCN_T) {
            float4 pb = pbp[2 * i];
            float4 p2 = pbp[2 * i + 1];
            float areap = (pb.z - pb.x) * (pb.w - pb.y);
            float iou = iou_exact(pb, areap, gx1, gy1, gx2, gy2, areag);
            float ec = INF_F;
            if (p2.w != 0.0f) ec = cost_exact(p2, gcx, gcy, scores[(size_t)i * NCLS + lab], iou);
            u64 k2 = (((u64)__float_as_uint(ec)) << 32) | (unsigned)i;
            if (k2 < lf[KTOP - 1]) {
                lf[KTOP - 1] = k2;
                #pragma unroll
                for (int s = KTOP - 1; s > 0; --s)
                    if (lf[s] < lf[s - 1]) { u64 t = lf[s]; lf[s] = lf[s - 1]; lf[s - 1] = t; }
            }
        }
        wave_merge_minN<KTOP>(lf, &wco[wid * KTOP], lane);
        __syncthreads();
        if (wid == 0) {
            int p = 0;
            for (int r = 0; r < KTOP; ++r) {
                u64 cur = (lane < NW8 && p < KTOP) ? wco[lane * KTOP + p] : ~0ull;
                u64 bm = wave_min_bc_u64(cur);
                if (cur == bm && bm != ~0ull) p++;
                if (lane == 0) csel[r] = bm;
            }
        }
        __syncthreads();
    }
    if (tid < KTOP) {
        u64* dpc = part_cost + ((size_t)j * SLC + slice) * KTOP;
        dpc[tid] = csel[tid];
    }
}

// ---------- merge 4 slices per GT, compute ks, scatter ----------
__global__ __launch_bounds__(64) void k_merge(
        const float* __restrict__ part_iou, const u64* __restrict__ part_cost,
        int* count, int* firstgt) {
    const int j = blockIdx.x;
    const int lane = threadIdx.x;
    float vi = (lane < SLC * KTOP) ? part_iou[(size_t)j * SLC * KTOP + lane] : NEGINF;
    float tsum = 0.0f;
    for (int r = 0; r < KTOP; ++r) {
        float bm = wave_max_bc_f32(vi);
        u64 m = __ballot(vi == bm && bm != NEGINF);
        int first = __ffsll(m) - 1;
        if (lane == first) vi = NEGINF;
        tsum += (bm == NEGINF) ? 0.0f : bm;   // descending-order sum (missing = 0, as ref)
    }
    int ks = (int)tsum;
    if (ks < 1) ks = 1;
    u64 kc = (lane < SLC * KTOP) ? part_cost[(size_t)j * SLC * KTOP + lane] : ~0ull;
    u64 mine = ~0ull;
    for (int r = 0; r < KTOP; ++r) {
        u64 bm = wave_min_bc_u64(kc);
        if (kc == bm && bm != ~0ull) kc = ~0ull;
        if (lane == r) mine = bm;
    }
    if (lane < KTOP && lane < ks && mine != ~0ull) {
        int idx = (int)(unsigned)(mine & 0xFFFFFFFFull);
        atomicAdd(&count[idx], 1);
        atomicMin(&firstgt[idx], j);
    }
}

// ---------- per-prior finalize; multi-matched priors -> worklist ----------
__global__ __launch_bounds__(256) void k_assign(
        const float4* __restrict__ pbp, const float* __restrict__ gt,
        const void* labels, const int* flag,
        const int* __restrict__ count, const int* __restrict__ firstgt,
        int* nmulti, int* mlist, float* __restrict__ out) {
    __shared__ float4 gbox[NGT];
    __shared__ int glab[NGT];
    __shared__ float gareas[NGT];
    int tid = threadIdx.x;
    int is64 = *flag;
    {
        float4 b = ((const float4*)gt)[tid];
        gbox[tid] = b;
        glab[tid] = get_label(labels, tid, is64);
        gareas[tid] = (b.z - b.x) * (b.w - b.y);
    }
    __syncthreads();
    int i = blockIdx.x * 256 + tid;
    if (i >= NPRI) return;
    float4 p2 = pbp[2 * i + 1];
    int v = (p2.w != 0.0f) ? 1 : 0;
    int c = count[i];
    float o0 = 0.0f, o1 = -INF_F, o2 = -1.0f;
    if (v && c == 1) {
        int j = firstgt[i];
        float4 pb = pbp[2 * i];
        float areap = (pb.z - pb.x) * (pb.w - pb.y);
        float4 g = gbox[j];
        float iw = fmaxf(fminf(pb.z, g.z) - fmaxf(pb.x, g.x), 0.0f);
        float ih = fmaxf(fminf(pb.w, g.w) - fmaxf(pb.y, g.y), 0.0f);
        float inter = iw * ih;
        float iou = inter / fmaxf(areap + gareas[j] - inter, 1e-6f);
        o0 = (float)(j + 1); o1 = iou; o2 = (float)glab[j];
    } else if (v && c > 1) {
        int pos = atomicAdd(nmulti, 1);
        mlist[pos] = i;
    }
    out[i] = o0;
    out[NPRI + i] = o1;
    out[2 * NPRI + i] = o2;
}

// ---------- one block per multi prior: block argmin over 256 GT costs ----------
__global__ __launch_bounds__(256) void k_multi(
        const float* __restrict__ scores,
        const float4* __restrict__ pbp, const float* __restrict__ gt,
        const void* labels, const int* flag,
        const int* __restrict__ nmulti, const int* __restrict__ mlist,
        float* __restrict__ out) {
    __shared__ float4 gbox[NGT];
    __shared__ int glab[NGT];
    __shared__ float gcxs[NGT], gcys[NGT], gareas[NGT];
    __shared__ u64 red4[4];
    const int tid = threadIdx.x;
    const int is64 = *flag;
    {
        float4 b = ((const float4*)gt)[tid];
        gbox[tid] = b;
        glab[tid] = get_label(labels, tid, is64);
        gcxs[tid] = (b.x + b.z) * 0.5f;
        gcys[tid] = (b.y + b.w) * 0.5f;
        gareas[tid] = (b.z - b.x) * (b.w - b.y);
    }
    __syncthreads();
    const int nm = *nmulti;
    const int j = tid;
    for (int m = blockIdx.x; m < nm; m += gridDim.x) {
        const int i = mlist[m];
        float4 pb = pbp[2 * i];
        float4 p2 = pbp[2 * i + 1];
        float areap = (pb.z - pb.x) * (pb.w - pb.y);

        float4 g = gbox[j];
        float iw = fmaxf(fminf(pb.z, g.z) - fmaxf(pb.x, g.x), 0.0f);
        float ih = fmaxf(fminf(pb.w, g.w) - fmaxf(pb.y, g.y), 0.0f);
        float inter = iw * ih;
        float iou = inter / fmaxf(areap + gareas[j] - inter, 1e-6f);
        float dx = p2.x - gcxs[j], dy = p2.y - gcys[j];
        float dist = sqrtf(dx * dx + dy * dy) / p2.z;
        float soft = exp2f((dist - 3.0f) * L10);
        float l = scores[(size_t)i * NCLS + glab[j]];
        float sig = 1.0f / (1.0f + expf(-l));
        float dd = iou - sig;
        float bce = fmaxf(l, 0.0f) - l * iou + log1pf(expf(-fabsf(l)));
        float cost = bce * (dd * dd) + (-logf(iou + EPS_F) * 3.0f) + soft;

        u64 key = (((u64)__float_as_uint(cost)) << 32) | (unsigned)j;
        u64 v = key;
        #pragma unroll
        for (int off = 32; off > 0; off >>= 1) {
            u64 o = __shfl_down(v, off, 64);
            v = (o < v) ? o : v;
        }
        if ((tid & 63) == 0) red4[tid >> 6] = v;
        __syncthreads();
        u64 best = red4[0];
        #pragma unroll
        for (int q = 1; q < 4; ++q) best = (red4[q] < best) ? red4[q] : best;
        if (key == best) {
            out[i] = (float)(j + 1);
            out[NPRI + i] = iou;
            out[2 * NPRI + i] = (float)glab[j];
        }
        __syncthreads();
    }
}

extern "C" void kernel_launch(void* const* d_in, const int* in_sizes, int n_in,
                              void* d_out, int out_size, void* d_ws, size_t ws_size,
                              hipStream_t stream) {
    const float* scores = (const float*)d_in[0];
    const float* priors = (const float*)d_in[1];
    const float* pboxes = (const float*)d_in[2];
    const float* gt     = (const float*)d_in[3];
    const void*  labels = d_in[4];
    float* out = (float*)d_out;

    char* ws = (char*)d_ws;
    size_t off = 0;
    auto alloc = [&](size_t bytes) { size_t o = off; off = (off + bytes + 255) & ~(size_t)255; return o; };
    int*    flag     = (int*)(ws + alloc(4));
    int*    nmulti   = (int*)(ws + alloc(4));
    int*    count    = (int*)(ws + alloc((size_t)NPRI * 4));
    int*    firstgt  = (int*)(ws + alloc((size_t)NPRI * 4));
    int*    mlist    = (int*)(ws + alloc((size_t)NPRI * 4));
    float*  part_iou = (float*)(ws + alloc((size_t)NGT * SLC * KTOP * 4));
    u64*    part_cost= (u64*)(ws + alloc((size_t)NGT * SLC * KTOP * 8));
    float4* pbp      = (float4*)(ws + alloc((size_t)NPRI * 32));
    (void)ws_size;

    hipLaunchKernelGGL(k_prep, dim3(PREP_BLKS), dim3(256), 0, stream,
                       priors, gt, labels, pboxes, pbp, count, firstgt, flag, nmulti);
    hipLaunchKernelGGL(k_scan, dim3(NGT, SLC), dim3(SCN_T), 0, stream,
                       scores, pbp, gt, labels, flag, part_iou, part_cost);
    hipLaunchKernelGGL(k_merge, dim3(NGT), dim3(64), 0, stream,
                       part_iou, part_cost, count, firstgt);
    hipLaunchKernelGGL(k_assign, dim3((NPRI + 255) / 256), dim3(256), 0, stream,
                       pbp, gt, labels, flag, count, firstgt, nmulti, mlist, out);
    hipLaunchKernelGGL(k_multi, dim3(256), dim3(256), 0, stream,
                       scores, pbp, gt, labels, flag, nmulti, mlist, out);
}

// Round 18
// 149.316 us; speedup vs baseline: 1.2662x; 1.0089x over previous
//
#include <hip/hip_runtime.h>
#include <cstdint>

#define NPRI 33600
#define NGT  256
#define NCLS 80
#define KTOP 13
#define INF_F 1.0e8f
#define EPS_F 1e-7f
#define L10 3.3219280948873623f
#define SLC  4
#define SLEN (NPRI / SLC)          // 8400
#define SCN_T 512
#define NW8 (SCN_T / 64)
#define NIT  ((SLEN + SCN_T - 1) / SCN_T)   // 17, uniform padded trip count
#define CAPI 1536                  // per-slice iou values
#define CAPC 512                   // per-slice cost candidates
#define RFIX 5.5f                  // fixed collect radius (strides); Dmax typically ~4.7
#define PREP_BLKS ((NPRI + 255) / 256)
#define NEGINF __int_as_float(0xff800000)

typedef unsigned long long u64;

__device__ __forceinline__ int get_label(const void* p, int j, int is64) {
    if (is64) return (int)((const long long*)p)[j];
    return ((const int*)p)[j];
}

// ---------- wave helpers (reduce + broadcast) ----------
__device__ __forceinline__ float wave_max_bc_f32(float v) {
    #pragma unroll
    for (int off = 32; off > 0; off >>= 1) v = fmaxf(v, __shfl_down(v, off, 64));
    return __int_as_float(__builtin_amdgcn_readfirstlane(__float_as_int(v)));
}
__device__ __forceinline__ u64 wave_min_bc_u64(u64 v) {
    #pragma unroll
    for (int off = 32; off > 0; off >>= 1) { u64 o = __shfl_down(v, off, 64); v = (o < v) ? o : v; }
    unsigned lo = (unsigned)__builtin_amdgcn_readfirstlane((int)(v & 0xffffffffull));
    unsigned hi = (unsigned)__builtin_amdgcn_readfirstlane((int)(v >> 32));
    return (((u64)hi) << 32) | lo;
}
// f32 multiset per-wave top-13: ballot single-lane elimination preserves duplicates
template<int NSL>
__device__ __forceinline__ void wave_merge_max13_f32(float (&l)[NSL], float* dst, int lane) {
    int p = 0;
    for (int r = 0; r < KTOP; ++r) {
        float cur = NEGINF;
        #pragma unroll
        for (int s = 0; s < NSL; ++s) if (s == p) cur = l[NSL - 1 - s];
        float bm = wave_max_bc_f32(cur);
        u64 m = __ballot(cur == bm && bm != NEGINF);
        int first = __ffsll(m) - 1;
        if (lane == first) p++;
        if (lane == 0) dst[r] = bm;
    }
}
// u64 per-wave top-13 min (keys idx-distinct -> single match per round)
template<int NSL>
__device__ __forceinline__ void wave_merge_minN(u64 (&l)[NSL], u64* dst, int lane) {
    int p = 0;
    for (int r = 0; r < KTOP; ++r) {
        u64 cur = ~0ull;
        #pragma unroll
        for (int s = 0; s < NSL; ++s) if (s == p) cur = l[s];
        u64 bm = wave_min_bc_u64(cur);
        if (cur == bm && bm != ~0ull) p++;
        if (lane == 0) dst[r] = bm;
    }
}

// ---------- exact formulas (verbatim round-2: bit-identical selection) ----------
__device__ __forceinline__ float iou_exact(float4 pb, float areap, float gx1, float gy1,
                                           float gx2, float gy2, float areag) {
    float iw = fmaxf(fminf(pb.z, gx2) - fmaxf(pb.x, gx1), 0.0f);
    float ih = fmaxf(fminf(pb.w, gy2) - fmaxf(pb.y, gy1), 0.0f);
    float inter = iw * ih;
    return inter / fmaxf(areap + areag - inter, 1e-6f);
}
__device__ __forceinline__ float cost_exact(float4 p2, float gcx, float gcy,
                                            float l, float iou) {
    float dx = p2.x - gcx, dy = p2.y - gcy;
    float dist = sqrtf(dx * dx + dy * dy) / p2.z;
    float soft = exp2f((dist - 3.0f) * L10);
    float sig = 1.0f / (1.0f + expf(-l));
    float dd = iou - sig;
    float bce = fmaxf(l, 0.0f) - l * iou + log1pf(expf(-fabsf(l)));
    float iouc = -logf(iou + EPS_F) * 3.0f;
    return bce * (dd * dd) + iouc + soft;
}

// ---------- prep: detect int64 + init + valid mask + packed array ----------
__global__ __launch_bounds__(256) void k_prep(
        const float* __restrict__ priors, const float* __restrict__ gt,
        const void* labels, const float* __restrict__ pboxes,
        float4* __restrict__ pbp,
        int* count, int* firstgt, int* flag, int* nmulti) {
    __shared__ float4 gbox[NGT];
    __shared__ int    gpad[NGT];
    __shared__ int    bad;
    const int tid = threadIdx.x;
    const int b = blockIdx.x;
    if (b == 0 && tid == 0) { bad = 0; *nmulti = 0; }
    {
        float4 bx = ((const float4*)gt)[tid];
        gbox[tid] = bx;
        gpad[tid] = ((bx.x + bx.y + bx.z + bx.w) > 0.0f) ? 1 : 0;
    }
    __syncthreads();
    if (b == 0 && tid < 128) {
        long long v = ((const long long*)labels)[tid];   // first 1024B: in-bounds either layout
        if (v < 0 || v >= NCLS) atomicOr(&bad, 1);
    }
    int i = b * 256 + tid;
    if (i < NPRI) {
        count[i] = 0; firstgt[i] = NGT;
        float4 pr = ((const float4*)priors)[i];
        float px = pr.x, py = pr.y;
        int v = 0;
        for (int j = 0; j < NGT; ++j) {
            float4 bx = gbox[j];
            float m = fminf(fminf(px - bx.x, py - bx.y), fminf(bx.z - px, bx.w - py));
            if (m > 0.0f && gpad[j]) { v = 1; break; }
        }
        pbp[2 * i]     = ((const float4*)pboxes)[i];
        pbp[2 * i + 1] = make_float4(px, py, pr.z, v ? 1.0f : 0.0f);
    }
    if (b == 0) {
        __syncthreads();
        if (tid == 0) *flag = bad ? 0 : 1;   // 1 => int64 layout
    }
}

// ---------- single-pass sliced scan; 2-deep prefetch pipeline; single-wave merges ----------
__global__ __launch_bounds__(SCN_T) void k_scan(
        const float* __restrict__ scores,
        const float4* __restrict__ pbp,
        const float* __restrict__ gt, const void* labels, const int* flag,
        float* __restrict__ part_iou, u64* __restrict__ part_cost) {
    const int tid = threadIdx.x, lane = tid & 63, wid = tid >> 6;
    const int j = blockIdx.x, slice = blockIdx.y;
    const int base = slice * SLEN;
    const int lim = base + SLEN;
    const int is64 = *flag;

    const float4 gb = ((const float4*)gt)[j];
    const float gx1 = gb.x, gy1 = gb.y, gx2 = gb.z, gy2 = gb.w;
    const float areag = (gx2 - gx1) * (gy2 - gy1);
    const float gcx = (gx1 + gx2) * 0.5f, gcy = (gy1 + gy2) * 0.5f;
    const int lab = get_label(labels, j, is64);

    __shared__ int s_ni, s_nc, s_mode;
    __shared__ float s_dmax;
    __shared__ float liou[CAPI];
    __shared__ int lcost[CAPC];
    __shared__ float wiof[NW8 * KTOP];   // fI fallback only
    __shared__ u64 wco[NW8 * KTOP];      // mode-2 fallback only
    __shared__ u64 csel[KTOP];
    if (tid == 0) { s_ni = 0; s_nc = 0; }
    __syncthreads();

    // ---- single pass, uniform 17-iter trip, 2-deep prefetch, wave-agg appends ----
    {
        const int i0 = base + tid;               // always < lim (SLEN > SCN_T)
        int ia1 = i0 + SCN_T; ia1 = (ia1 < lim) ? ia1 : i0;   // clamped, in-bounds
        float4 pb_c = pbp[2 * i0],  p2_c = pbp[2 * i0 + 1];
        float4 pb_n = pbp[2 * ia1], p2_n = pbp[2 * ia1 + 1];
        for (int it = 0; it < NIT; ++it) {
            int i = i0 + it * SCN_T;
            int ipre = i + 2 * SCN_T;
            int ic = (ipre < lim) ? ipre : i0;   // clamped prefetch address (always valid)
            float4 pb_p = pbp[2 * ic];
            float4 p2_p = pbp[2 * ic + 1];       // two loads in flight during ballots

            bool inb = (i < lim);
            float iou = 0.0f;
            bool pc = false;
            if (inb) {
                float areap = (pb_c.z - pb_c.x) * (pb_c.w - pb_c.y);
                float iw = fmaxf(fminf(pb_c.z, gx2) - fmaxf(pb_c.x, gx1), 0.0f);
                float ih = fmaxf(fminf(pb_c.w, gy2) - fmaxf(pb_c.y, gy1), 0.0f);
                float inter = iw * ih;
                iou = inter / fmaxf(areap + areag - inter, 1e-6f);   // exact
                if (p2_c.w != 0.0f) {
                    float dx = p2_c.x - gcx, dy = p2_c.y - gcy;
                    float rad = p2_c.z * RFIX;
                    pc = (dx * dx + dy * dy <= rad * rad * (1.0f + 1e-5f));
                }
            }
            bool pi = inb && (iou > 0.0f);
            u64 mi = __ballot(pi);
            if (mi) {
                int lead = __ffsll(mi) - 1;
                int cnt = __popcll(mi);
                int bs = 0;
                if (lane == lead) bs = atomicAdd(&s_ni, cnt);
                bs = __shfl(bs, lead, 64);
                if (pi) {
                    int p = bs + __popcll(mi & ((1ull << lane) - 1ull));
                    if (p < CAPI) liou[p] = iou;
                }
            }
            u64 mc = __ballot(pc);
            if (mc) {
                int lead = __ffsll(mc) - 1;
                int cnt = __popcll(mc);
                int bs = 0;
                if (lane == lead) bs = atomicAdd(&s_nc, cnt);
                bs = __shfl(bs, lead, 64);
                if (pc) {
                    int p = bs + __popcll(mc & ((1ull << lane) - 1ull));
                    if (p < CAPC) lcost[p] = i;
                }
            }
            pb_c = pb_n; p2_c = p2_n;
            pb_n = pb_p; p2_n = p2_p;
        }
    }
    __syncthreads();
    const int ni = s_ni, nc = s_nc;
    const int ncc = (nc < CAPC) ? nc : CAPC;
    const bool fI = (ni > CAPI);

    // ---- parallel single-wave merges: wave 0 = cost, wave 1 = iou ----
    if (wid == 0) {
        u64 lf[KTOP];
        #pragma unroll
        for (int s = 0; s < KTOP; ++s) lf[s] = ~0ull;
        for (int k = lane; k < ncc; k += 64) {   // <=8 per lane; 13-deep list complete
            int i = lcost[k];
            float4 pb = pbp[2 * i];
            float4 p2 = pbp[2 * i + 1];
            float areap = (pb.z - pb.x) * (pb.w - pb.y);
            float iou = iou_exact(pb, areap, gx1, gy1, gx2, gy2, areag);
            float ec = cost_exact(p2, gcx, gcy, scores[(size_t)i * NCLS + lab], iou);
            u64 ck = (((u64)__float_as_uint(ec)) << 32) | (unsigned)i;
            if (ck < lf[KTOP - 1]) {
                lf[KTOP - 1] = ck;
                #pragma unroll
                for (int s = KTOP - 1; s > 0; --s)
                    if (lf[s] < lf[s - 1]) { u64 t = lf[s]; lf[s] = lf[s - 1]; lf[s - 1] = t; }
            }
        }
        wave_merge_minN<KTOP>(lf, csel, lane);
        if (lane == 0) {
            u64 tk = csel[KTOP - 1];
            int mode; float dmax = 0.0f;
            if (tk == ~0ull) mode = 2;               // <13 candidates in RFIX ball
            else {
                float tau = __uint_as_float((unsigned)(tk >> 32));
                if (!(tau < 9.0e7f)) mode = 2;       // INF-ambiguity zone
                else {
                    dmax = 3.0f + __log2f(tau + 1e-5f) * (1.0f / L10) + 4e-3f;
                    mode = (dmax > RFIX || nc > CAPC) ? 1 : 0;
                }
            }
            s_mode = mode; s_dmax = dmax;
        }
    } else if (wid == 1 && !fI) {
        float lf[KTOP];
        #pragma unroll
        for (int s = 0; s < KTOP; ++s) lf[s] = NEGINF;
        int nn = (ni < CAPI) ? ni : CAPI;
        for (int k = lane; k < nn; k += 64) {    // <=24 per lane; 13-deep retains any lane's top-13
            float v = liou[k];
            if (v > lf[0]) {
                lf[0] = v;
                #pragma unroll
                for (int s = 0; s < KTOP - 1; ++s)
                    if (lf[s] > lf[s + 1]) { float t = lf[s]; lf[s] = lf[s + 1]; lf[s + 1] = t; }
            }
        }
        wave_merge_max13_f32<KTOP>(lf, part_iou + ((size_t)j * SLC + slice) * KTOP, lane);
    }
    __syncthreads();

    if (fI) {   // rare: iou list overflowed -> exact full-slice scan (two-stage merge)
        float lf[KTOP];
        #pragma unroll
        for (int s = 0; s < KTOP; ++s) lf[s] = NEGINF;
        for (int i = base + tid; i < lim; i += SCN_T) {
            float4 pb = pbp[2 * i];
            float areap = (pb.z - pb.x) * (pb.w - pb.y);
            float iou = iou_exact(pb, areap, gx1, gy1, gx2, gy2, areag);
            if (iou > lf[0]) {
                lf[0] = iou;
                #pragma unroll
                for (int s = 0; s < KTOP - 1; ++s)
                    if (lf[s] > lf[s + 1]) { float t = lf[s]; lf[s] = lf[s + 1]; lf[s + 1] = t; }
            }
        }
        wave_merge_max13_f32<KTOP>(lf, &wiof[wid * KTOP], lane);
        __syncthreads();
        if (wid == 0) {
            float* dpi = part_iou + ((size_t)j * SLC + slice) * KTOP;
            int p = 0;
            for (int r = 0; r < KTOP; ++r) {
                float cur = (lane < NW8 && p < KTOP) ? wiof[lane * KTOP + p] : NEGINF;
                float bm = wave_max_bc_f32(cur);
                u64 m = __ballot(cur == bm && bm != NEGINF);
                int first = __ffsll(m) - 1;
                if (lane == first) p++;
                if (lane == 0) dpi[r] = bm;
            }
        }
        __syncthreads();
    }

    int mode = s_mode;
    if (mode == 1) {   // re-collect at the sound radius Dmax' (rare)
        const float dmax = s_dmax;
        if (tid == 0) s_nc = 0;
        __syncthreads();
        for (int i = base + tid; i < lim; i += SCN_T) {
            float4 p2 = pbp[2 * i + 1];
            if (p2.w != 0.0f) {
                float dx = p2.x - gcx, dy = p2.y - gcy;
                float rad = p2.z * dmax;
                if (dx * dx + dy * dy <= rad * rad * (1.0f + 1e-5f)) {
                    int p = atomicAdd(&s_nc, 1);
                    if (p < CAPC) lcost[p] = i;
                }
            }
        }
        __syncthreads();
        int nc2 = s_nc;
        if (nc2 <= CAPC) {
            if (wid == 0) {
                u64 lf[KTOP];
                #pragma unroll
                for (int s = 0; s < KTOP; ++s) lf[s] = ~0ull;
                for (int k = lane; k < nc2; k += 64) {
                    int i = lcost[k];
                    float4 pb = pbp[2 * i];
                    float4 p2 = pbp[2 * i + 1];
                    float areap = (pb.z - pb.x) * (pb.w - pb.y);
                    float iou = iou_exact(pb, areap, gx1, gy1, gx2, gy2, areag);
                    float ec = cost_exact(p2, gcx, gcy, scores[(size_t)i * NCLS + lab], iou);
                    u64 ck = (((u64)__float_as_uint(ec)) << 32) | (unsigned)i;
                    if (ck < lf[KTOP - 1]) {
                        lf[KTOP - 1] = ck;
                        #pragma unroll
                        for (int s = KTOP - 1; s > 0; --s)
                            if (lf[s] < lf[s - 1]) { u64 t = lf[s]; lf[s] = lf[s - 1]; lf[s - 1] = t; }
                    }
                }
                wave_merge_minN<KTOP>(lf, csel, lane);
            }
        } else {
            mode = 2;   // uniform (s_nc shared)
        }
        __syncthreads();
    }
    if (mode == 2) {   // exact full slice scan (round-2 semantics; correctness net)
        u64 lf[KTOP];
        #pragma unroll
        for (int s = 0; s < KTOP; ++s) lf[s] = ~0ull;
        for (int i = base + tid; i < lim; i += SCN_T) {
            float4 pb = pbp[2 * i];
            float4 p2 = pbp[2 * i + 1];
            float areap = (pb.z - pb.x) * (pb.w - pb.y);
            float iou = iou_exact(pb, areap, gx1, gy1, gx2, gy2, areag);
            float ec = INF_F;
            if (p2.w != 0.0f) ec = cost_exact(p2, gcx, gcy, scores[(size_t)i * NCLS + lab], iou);
            u64 k2 = (((u64)__float_as_uint(ec)) << 32) | (unsigned)i;
            if (k2 < lf[KTOP - 1]) {
                lf[KTOP - 1] = k2;
                #pragma unroll
                for (int s = KTOP - 1; s > 0; --s)
                    if (lf[s] < lf[s - 1]) { u64 t = lf[s]; lf[s] = lf[s - 1]; lf[s - 1] = t; }
            }
        }
        wave_merge_minN<KTOP>(lf, &wco[wid * KTOP], lane);
        __syncthreads();
        if (wid == 0) {
            int p = 0;
            for (int r = 0; r < KTOP; ++r) {
                u64 cur = (lane < NW8 && p < KTOP) ? wco[lane * KTOP + p] : ~0ull;
                u64 bm = wave_min_bc_u64(cur);
                if (cur == bm && bm != ~0ull) p++;
                if (lane == 0) csel[r] = bm;
            }
        }
        __syncthreads();
    }
    if (tid < KTOP) {
        u64* dpc = part_cost + ((size_t)j * SLC + slice) * KTOP;
        dpc[tid] = csel[tid];
    }
}

// ---------- merge 4 slices per GT, compute ks, scatter ----------
__global__ __launch_bounds__(64) void k_merge(
        const float* __restrict__ part_iou, const u64* __restrict__ part_cost,
        int* count, int* firstgt) {
    const int j = blockIdx.x;
    const int lane = threadIdx.x;
    float vi = (lane < SLC * KTOP) ? part_iou[(size_t)j * SLC * KTOP + lane] : NEGINF;
    float tsum = 0.0f;
    for (int r = 0; r < KTOP; ++r) {
        float bm = wave_max_bc_f32(vi);
        u64 m = __ballot(vi == bm && bm != NEGINF);
        int first = __ffsll(m) - 1;
        if (lane == first) vi = NEGINF;
        tsum += (bm == NEGINF) ? 0.0f : bm;   // descending-order sum (missing = 0, as ref)
    }
    int ks = (int)tsum;
    if (ks < 1) ks = 1;
    u64 kc = (lane < SLC * KTOP) ? part_cost[(size_t)j * SLC * KTOP + lane] : ~0ull;
    u64 mine = ~0ull;
    for (int r = 0; r < KTOP; ++r) {
        u64 bm = wave_min_bc_u64(kc);
        if (kc == bm && bm != ~0ull) kc = ~0ull;
        if (lane == r) mine = bm;
    }
    if (lane < KTOP && lane < ks && mine != ~0ull) {
        int idx = (int)(unsigned)(mine & 0xFFFFFFFFull);
        atomicAdd(&count[idx], 1);
        atomicMin(&firstgt[idx], j);
    }
}

// ---------- per-prior finalize; multi-matched priors -> worklist ----------
__global__ __launch_bounds__(256) void k_assign(
        const float4* __restrict__ pbp, const float* __restrict__ gt,
        const void* labels, const int* flag,
        const int* __restrict__ count, const int* __restrict__ firstgt,
        int* nmulti, int* mlist, float* __restrict__ out) {
    __shared__ float4 gbox[NGT];
    __shared__ int glab[NGT];
    __shared__ float gareas[NGT];
    int tid = threadIdx.x;
    int is64 = *flag;
    {
        float4 b = ((const float4*)gt)[tid];
        gbox[tid] = b;
        glab[tid] = get_label(labels, tid, is64);
        gareas[tid] = (b.z - b.x) * (b.w - b.y);
    }
    __syncthreads();
    int i = blockIdx.x * 256 + tid;
    if (i >= NPRI) return;
    float4 p2 = pbp[2 * i + 1];
    int v = (p2.w != 0.0f) ? 1 : 0;
    int c = count[i];
    float o0 = 0.0f, o1 = -INF_F, o2 = -1.0f;
    if (v && c == 1) {
        int j = firstgt[i];
        float4 pb = pbp[2 * i];
        float areap = (pb.z - pb.x) * (pb.w - pb.y);
        float4 g = gbox[j];
        float iw = fmaxf(fminf(pb.z, g.z) - fmaxf(pb.x, g.x), 0.0f);
        float ih = fmaxf(fminf(pb.w, g.w) - fmaxf(pb.y, g.y), 0.0f);
        float inter = iw * ih;
        float iou = inter / fmaxf(areap + gareas[j] - inter, 1e-6f);
        o0 = (float)(j + 1); o1 = iou; o2 = (float)glab[j];
    } else if (v && c > 1) {
        int pos = atomicAdd(nmulti, 1);
        mlist[pos] = i;
    }
    out[i] = o0;
    out[NPRI + i] = o1;
    out[2 * NPRI + i] = o2;
}

// ---------- one block per multi prior: block argmin over 256 GT costs ----------
__global__ __launch_bounds__(256) void k_multi(
        const float* __restrict__ scores,
        const float4* __restrict__ pbp, const float* __restrict__ gt,
        const void* labels, const int* flag,
        const int* __restrict__ nmulti, const int* __restrict__ mlist,
        float* __restrict__ out) {
    __shared__ float4 gbox[NGT];
    __shared__ int glab[NGT];
    __shared__ float gcxs[NGT], gcys[NGT], gareas[NGT];
    __shared__ u64 red4[4];
    const int tid = threadIdx.x;
    const int is64 = *flag;
    {
        float4 b = ((const float4*)gt)[tid];
        gbox[tid] = b;
        glab[tid] = get_label(labels, tid, is64);
        gcxs[tid] = (b.x + b.z) * 0.5f;
        gcys[tid] = (b.y + b.w) * 0.5f;
        gareas[tid] = (b.z - b.x) * (b.w - b.y);
    }
    __syncthreads();
    const int nm = *nmulti;
    const int j = tid;
    for (int m = blockIdx.x; m < nm; m += gridDim.x) {
        const int i = mlist[m];
        float4 pb = pbp[2 * i];
        float4 p2 = pbp[2 * i + 1];
        float areap = (pb.z - pb.x) * (pb.w - pb.y);

        float4 g = gbox[j];
        float iw = fmaxf(fminf(pb.z, g.z) - fmaxf(pb.x, g.x), 0.0f);
        float ih = fmaxf(fminf(pb.w, g.w) - fmaxf(pb.y, g.y), 0.0f);
        float inter = iw * ih;
        float iou = inter / fmaxf(areap + gareas[j] - inter, 1e-6f);
        float dx = p2.x - gcxs[j], dy = p2.y - gcys[j];
        float dist = sqrtf(dx * dx + dy * dy) / p2.z;
        float soft = exp2f((dist - 3.0f) * L10);
        float l = scores[(size_t)i * NCLS + glab[j]];
        float sig = 1.0f / (1.0f + expf(-l));
        float dd = iou - sig;
        float bce = fmaxf(l, 0.0f) - l * iou + log1pf(expf(-fabsf(l)));
        float cost = bce * (dd * dd) + (-logf(iou + EPS_F) * 3.0f) + soft;

        u64 key = (((u64)__float_as_uint(cost)) << 32) | (unsigned)j;
        u64 v = key;
        #pragma unroll
        for (int off = 32; off > 0; off >>= 1) {
            u64 o = __shfl_down(v, off, 64);
            v = (o < v) ? o : v;
        }
        if ((tid & 63) == 0) red4[tid >> 6] = v;
        __syncthreads();
        u64 best = red4[0];
        #pragma unroll
        for (int q = 1; q < 4; ++q) best = (red4[q] < best) ? red4[q] : best;
        if (key == best) {
            out[i] = (float)(j + 1);
            out[NPRI + i] = iou;
            out[2 * NPRI + i] = (float)glab[j];
        }
        __syncthreads();
    }
}

extern "C" void kernel_launch(void* const* d_in, const int* in_sizes, int n_in,
                              void* d_out, int out_size, void* d_ws, size_t ws_size,
                              hipStream_t stream) {
    const float* scores = (const float*)d_in[0];
    const float* priors = (const float*)d_in[1];
    const float* pboxes = (const float*)d_in[2];
    const float* gt     = (const float*)d_in[3];
    const void*  labels = d_in[4];
    float* out = (float*)d_out;

    char* ws = (char*)d_ws;
    size_t off = 0;
    auto alloc = [&](size_t bytes) { size_t o = off; off = (off + bytes + 255) & ~(size_t)255; return o; };
    int*    flag     = (int*)(ws + alloc(4));
    int*    nmulti   = (int*)(ws + alloc(4));
    int*    count    = (int*)(ws + alloc((size_t)NPRI * 4));
    int*    firstgt  = (int*)(ws + alloc((size_t)NPRI * 4));
    int*    mlist    = (int*)(ws + alloc((size_t)NPRI * 4));
    float*  part_iou = (float*)(ws + alloc((size_t)NGT * SLC * KTOP * 4));
    u64*    part_cost= (u64*)(ws + alloc((size_t)NGT * SLC * KTOP * 8));
    float4* pbp      = (float4*)(ws + alloc((size_t)NPRI * 32));
    (void)ws_size;

    hipLaunchKernelGGL(k_prep, dim3(PREP_BLKS), dim3(256), 0, stream,
                       priors, gt, labels, pboxes, pbp, count, firstgt, flag, nmulti);
    hipLaunchKernelGGL(k_scan, dim3(NGT, SLC), dim3(SCN_T), 0, stream,
                       scores, pbp, gt, labels, flag, part_iou, part_cost);
    hipLaunchKernelGGL(k_merge, dim3(NGT), dim3(64), 0, stream,
                       part_iou, part_cost, count, firstgt);
    hipLaunchKernelGGL(k_assign, dim3((NPRI + 255) / 256), dim3(256), 0, stream,
                       pbp, gt, labels, flag, count, firstgt, nmulti, mlist, out);
    hipLaunchKernelGGL(k_multi, dim3(256), dim3(256), 0, stream,
                       scores, pbp, gt, labels, flag, nmulti, mlist, out);
}